// Round 21
// baseline (29033.179 us; speedup 1.0000x reference)
//
#include <hip/hip_runtime.h>
#include <stdint.h>

#define TLEN   4096
#define DMODEL 2048
#define NPROJ  1024
#define NHEADS 16
#define IDXD   64
#define TOPK   128
#define KC     512   // BLIS/AOCL zen f32 kc; K=2048 -> clean panels {512x4}

// monotonic f32 -> orderable u32 (no NaN/Inf in this data)
__device__ __forceinline__ unsigned int f32_ord(float f) {
  unsigned int u = __float_as_uint(f);
  return (u & 0x80000000u) ? ~u : (u | 0x80000000u);
}

// BLIS-style sgemm K-loop: K=2048 split into clean panels {512,512,512,512}.
// Per element: each panel is a zero-init sequential FMA chain (micro-kernel
// accumulates k ascending, one accumulator per C element); panel results
// combined left-to-right with plain f32 adds (beta=0 first, beta=1 after).
// One thread per output element. X laid out (16, T, 128) f32; W (2048,1024).
// TRANS==0: out[h][t][d]   TRANS==1: out[h][d][t]
template<int TRANS>
__global__ __launch_bounds__(256)
void proj_blas(const float* __restrict__ X, const float* __restrict__ W,
               float* __restrict__ out) {
  const int gid = blockIdx.x * 256 + threadIdx.x;   // t*1024 + j
  const int t = gid >> 10;
  const int j = gid & 1023;
  const int h = j >> 6, d = j & 63;

  float ctotal = 0.0f;
  for (int k0 = 0; k0 < DMODEL; k0 += KC) {
    float acc = 0.0f;
    #pragma unroll 4
    for (int kk = 0; kk < KC; kk++) {
      const int c = k0 + kk;
      const float a = X[((size_t)(c >> 7) * TLEN + t) * 128 + (c & 127)];
      const float w = W[(size_t)c * NPROJ + j];
      acc = fmaf(a, w, acc);
    }
    ctotal = (k0 == 0) ? acc : __fadd_rn(ctotal, acc);
  }

  if (TRANS == 0)
    out[((size_t)h * TLEN + t) * IDXD + d] = ctotal;
  else
    out[((size_t)h * IDXD + d) * TLEN + t] = ctotal;
}

// Scores: einsum translated as batched matmul -> BLIS sgemm with K=64:
// K < kc -> SINGLE panel -> pure sequential f32 FMA chain over d = 0..63,
// zero-init (beta=0). Then brute-force exact top-128 (verified R6-R19
// scaffold): value desc, ties index-ascending (jax stable).
__global__ __launch_bounds__(512)
void score_topk(const float* __restrict__ qidx,   // [H][T][64] f32
                const float* __restrict__ kT,     // [H][64][T] f32
                int* __restrict__ out) {          // [H][T][128]
  __shared__ float qs[IDXD];
  __shared__ unsigned long long key[TLEN];        // 32 KB packed keys
  __shared__ unsigned long long wk[8];
  __shared__ int sel[TOPK];

  const int bid = blockIdx.x;                     // h*4096 + t
  const int h = bid >> 12;
  const int t = bid & 4095;
  const int tid = threadIdx.x;

  if (tid < IDXD) qs[tid] = qidx[((size_t)h * TLEN + t) * IDXD + tid];
  __syncthreads();

  const float* kb = kT + (size_t)h * IDXD * TLEN;

  #pragma unroll
  for (int s = 0; s < 8; s++) {
    const int tk = s * 512 + tid;
    float sc = 0.0f;
    #pragma unroll
    for (int d = 0; d < IDXD; d++)
      sc = fmaf(qs[d], kb[(size_t)d * TLEN + tk], sc);   // strict d=0..63 chain

    // pack: value desc primary; ~idx secondary -> smaller index wins ties
    key[tk] = ((unsigned long long)f32_ord(sc) << 32) | (unsigned int)(~tk);
  }
  __syncthreads();

  // ---- brute-force top-128: 128 iterations of block-wide packed-key max ----
  const int lane64 = tid & 63, wave = tid >> 6;
  for (int it = 0; it < TOPK; it++) {
    unsigned long long bk = 0ull;
    const int base = tid * 8;
    #pragma unroll
    for (int e = 0; e < 8; e++) {
      unsigned long long k = key[base + e];
      if (k > bk) bk = k;
    }
    #pragma unroll
    for (int off = 32; off > 0; off >>= 1) {
      unsigned long long ok = __shfl_down(bk, off);
      if (ok > bk) bk = ok;
    }
    if (lane64 == 0) wk[wave] = bk;
    __syncthreads();
    if (tid == 0) {
      unsigned long long k0 = wk[0];
      for (int w = 1; w < 8; w++) if (wk[w] > k0) k0 = wk[w];
      unsigned int idx = ~(unsigned int)k0;
      sel[it] = (int)idx;
      key[idx] = 0ull;   // remove winner (real packed keys are never 0)
    }
    __syncthreads();
  }

  if (tid < TOPK) out[((size_t)h * TLEN + t) * TOPK + tid] = sel[tid];
}

extern "C" void kernel_launch(void* const* d_in, const int* in_sizes, int n_in,
                              void* d_out, int out_size, void* d_ws, size_t ws_size,
                              hipStream_t stream) {
  const float* q  = (const float*)d_in[0];
  const float* k  = (const float*)d_in[1];
  const float* Wq = (const float*)d_in[2];
  const float* Wk = (const float*)d_in[3];

  const size_t idx_elems = (size_t)NHEADS * TLEN * IDXD;   // 4M elements
  if (ws_size < 2 * idx_elems * sizeof(float)) return;     // need 32MB scratch

  float* qidx = (float*)d_ws;                  // [H][T][64] f32, 16MB
  float* kT   = (float*)d_ws + idx_elems;      // [H][64][T] f32, 16MB

  const int proj_blocks = (TLEN * NPROJ) / 256;            // 16384
  proj_blas<0><<<proj_blocks, 256, 0, stream>>>(q, Wq, qidx);
  proj_blas<1><<<proj_blocks, 256, 0, stream>>>(k, Wk, kT);

  score_topk<<<NHEADS * TLEN, 512, 0, stream>>>(qidx, kT, (int*)d_out);
}

// Round 22
// 3349.002 us; speedup vs baseline: 8.6692x; 8.6692x over previous
//
#include <hip/hip_runtime.h>
#include <stdint.h>

#define TLEN   4096
#define DMODEL 2048
#define NPROJ  1024
#define NHEADS 16
#define IDXD   64
#define TOPK   128
#define KC     512   // BLIS/AOCL zen f32 kc (verified R21: panels {512x4})

// monotonic f32 -> orderable u32 (no NaN/Inf in this data)
__device__ __forceinline__ unsigned int f32_ord(float f) {
  unsigned int u = __float_as_uint(f);
  return (u & 0x80000000u) ? ~u : (u | 0x80000000u);
}

// Tiled projection GEMM, bit-exact to verified R21 arithmetic:
// per output element: 4 K-panels of 512, each a zero-init sequential FMA
// chain (k ascending), panels combined left-to-right with plain f32 adds.
// Tile structure proven bitwise == naive sequential chain (R1 == R12);
// only the panel fold (every 16 k-tiles) is added, matching R21's proj_blas.
// X laid out (16, T, 128) f32; W (2048, 1024) f32.
// TRANS==0: out[h][t][d]   TRANS==1: out[h][d][t]
template<int TRANS>
__global__ __launch_bounds__(256)
void proj_gemm(const float* __restrict__ X, const float* __restrict__ W,
               float* __restrict__ out) {
  __shared__ float smem[64 * 65];                // As/Bs then reused as cs
  float (*As)[64] = (float(*)[64])smem;          // [k][m]
  float (*Bs)[64] = (float(*)[64])(smem + 2048); // [k][n]
  float (*cs)[65] = (float(*)[65])smem;          // transpose staging

  const int tid = threadIdx.x;
  const int bx = blockIdx.x;   // head (64 output cols)
  const int by = blockIdx.y;   // t-tile

  const int tx = tid & 15;
  const int ty = tid >> 4;

  float acc[4][4] = {};        // current-panel accumulators
  float ctot[4][4];            // folded panel total

  const int lt = tid & 7;
  const int tt = tid >> 3;
  const int bc = tid >> 4;
  const int bn = (tid & 15) * 4;

  for (int ks = 0; ks < DMODEL; ks += 32) {
    const int h2 = ks >> 7;
    const int offs = ks & 127;
    {
      const float* ap = X + ((size_t)h2 * TLEN + (size_t)by * 64) * 128 + offs + lt * 4;
      #pragma unroll
      for (int i = 0; i < 2; i++) {
        int t = tt + i * 32;
        float4 v = *(const float4*)(ap + (size_t)t * 128);
        As[lt * 4 + 0][t] = v.x;
        As[lt * 4 + 1][t] = v.y;
        As[lt * 4 + 2][t] = v.z;
        As[lt * 4 + 3][t] = v.w;
      }
    }
    {
      #pragma unroll
      for (int i = 0; i < 2; i++) {
        int c = ks + bc + i * 16;
        float4 v = *(const float4*)(W + (size_t)c * NPROJ + bx * 64 + bn);
        *(float4*)&Bs[bc + i * 16][bn] = v;
      }
    }
    __syncthreads();
    #pragma unroll
    for (int kk = 0; kk < 32; kk++) {
      float4 a = *(const float4*)&As[kk][ty * 4];
      float4 b = *(const float4*)&Bs[kk][tx * 4];
      const float av[4] = {a.x, a.y, a.z, a.w};
      const float bv[4] = {b.x, b.y, b.z, b.w};
      #pragma unroll
      for (int i = 0; i < 4; i++)
        #pragma unroll
        for (int j = 0; j < 4; j++)
          acc[i][j] = fmaf(av[i], bv[j], acc[i][j]);
    }
    __syncthreads();
    if (((ks + 32) & (KC - 1)) == 0) {           // panel boundary: 512,1024,...
      const bool first = (ks + 32 == KC);
      #pragma unroll
      for (int i = 0; i < 4; i++)
        #pragma unroll
        for (int j = 0; j < 4; j++) {
          ctot[i][j] = first ? acc[i][j] : __fadd_rn(ctot[i][j], acc[i][j]);
          acc[i][j] = 0.0f;
        }
    }
  }

  if (TRANS == 0) {
    #pragma unroll
    for (int i = 0; i < 4; i++) {
      int m = by * 64 + ty * 4 + i;
      float4 v = make_float4(ctot[i][0], ctot[i][1], ctot[i][2], ctot[i][3]);
      *(float4*)(out + ((size_t)bx * TLEN + m) * IDXD + tx * 4) = v;
    }
  } else {
    #pragma unroll
    for (int i = 0; i < 4; i++)
      #pragma unroll
      for (int j = 0; j < 4; j++)
        cs[ty * 4 + i][tx * 4 + j] = ctot[i][j];
    __syncthreads();
    const int mm = tid & 63;
    const int dg = tid >> 6;
    #pragma unroll
    for (int p = 0; p < 16; p++) {
      int d = dg + p * 4;
      out[((size_t)bx * IDXD + d) * TLEN + (size_t)by * 64 + mm] = cs[mm][d];
    }
  }
}

// Fused score + exact top-128: one block per (head, 8 q-rows). Scores in
// registers with the verified strict d=0..63 sequential FMA chain. Selection:
// 4-pass radix on 32-bit orderable key + index-ranked ties + bitonic sort —
// machinery proven bit-identical to brute force (R3/R4 vs R5).
__global__ __launch_bounds__(512)
void score_topk(const float* __restrict__ qidx,  // [H][T][64]
                const float* __restrict__ kT,    // [H][64][T]
                int* __restrict__ out) {         // [H][T][128]
  __shared__ float qs[8][64];
  __shared__ unsigned int hist[8][257];          // +1 pad for serial scans
  __shared__ unsigned int ebuf[8][128];          // ==pivot indices
  __shared__ unsigned long long cand[8][TOPK];   // (key<<32)|~idx
  __shared__ unsigned int pivot[8];
  __shared__ int rrem[8];
  __shared__ int gcnt[8];
  __shared__ int ecnt[8];

  const int tid = threadIdx.x;

  // XCD swizzle: 2 heads per XCD -> kT head slices L2-resident
  const int flat = blockIdx.y * gridDim.x + blockIdx.x;   // 0..8191
  const int nf   = (flat & 7) * 1024 + (flat >> 3);
  const int h    = nf >> 9;          // 512 tiles per head
  const int t0   = (nf & 511) * 8;

  if (tid < 8) { pivot[tid] = 0; rrem[tid] = TOPK; gcnt[tid] = 0; ecnt[tid] = 0; }
  // sentinel: key=0 (sorts last), idx=0 (in-range) -> packed 0x00000000FFFFFFFF
  for (int i = tid; i < 8 * TOPK; i += 512)
    ((unsigned long long*)cand)[i] = 0x00000000FFFFFFFFull;
  qs[tid >> 6][tid & 63] =
      qidx[((size_t)h * TLEN + t0 + (tid >> 6)) * IDXD + (tid & 63)];
  __syncthreads();

  // ---- phase 1: scores, strict d-ascending chain. k index = s*512 + tid ----
  float sc[8][8] = {};
  const float* kb = kT + (size_t)h * IDXD * TLEN + tid;
  for (int d = 0; d < IDXD; d++) {
    float kv[8];
    #pragma unroll
    for (int s = 0; s < 8; s++) kv[s] = kb[(size_t)d * TLEN + s * 512];
    #pragma unroll
    for (int q = 0; q < 8; q++) {
      float qv = qs[q][d];
      #pragma unroll
      for (int s = 0; s < 8; s++) sc[q][s] = fmaf(qv, kv[s], sc[q][s]);
    }
  }

  unsigned int ku[8][8];
  #pragma unroll
  for (int q = 0; q < 8; q++)
    #pragma unroll
    for (int s = 0; s < 8; s++) ku[q][s] = f32_ord(sc[q][s]);

  // ---- phase 2: 4-pass radix select (MSB first) per row ----
  for (int pass = 0; pass < 4; pass++) {
    const int shift = 24 - 8 * pass;
    const unsigned int pmask = (pass == 0) ? 0u : (0xFFFFFFFFu << (shift + 8));
    for (int i = tid; i < 8 * 257; i += 512) ((unsigned int*)hist)[i] = 0;
    __syncthreads();
    #pragma unroll
    for (int q = 0; q < 8; q++) {
      unsigned int pv = pivot[q];
      #pragma unroll
      for (int s = 0; s < 8; s++) {
        unsigned int k = ku[q][s];
        if ((k & pmask) == pv)
          atomicAdd(&hist[q][(k >> shift) & 255], 1u);
      }
    }
    __syncthreads();
    if (tid < 8) { // serial descending scan; 8 rows in parallel (padded)
      int rq = rrem[tid];
      int c = 0, b = 0;
      for (int j = 255; j >= 0; j--) {
        int hc = (int)hist[tid][j];
        if (c + hc >= rq) { b = j; break; }
        c += hc;
      }
      rrem[tid] = rq - c;
      pivot[tid] |= (unsigned int)b << shift;
    }
    __syncthreads();
  }

  // ---- phase 3: gather. > pivot all in; == pivot take smallest indices ----
  #pragma unroll
  for (int q = 0; q < 8; q++) {
    unsigned int pv = pivot[q];
    #pragma unroll
    for (int s = 0; s < 8; s++) {
      unsigned int k = ku[q][s];
      unsigned int idx = s * 512 + tid;
      if (k > pv) {
        int pos = atomicAdd(&gcnt[q], 1);
        if (pos < TOPK)
          cand[q][pos] = ((unsigned long long)k << 32) | (unsigned int)(~idx);
      } else if (k == pv) {
        int e = atomicAdd(&ecnt[q], 1);
        if (e < 128) ebuf[q][e] = idx;
      }
    }
  }
  __syncthreads();
  {
    // wave wv owns row wv: rank equal-indices, keep rrem smallest
    const int wv = tid >> 6;
    const int lane = tid & 63;
    int e = ecnt[wv]; if (e > 128) e = 128;
    const int rq = rrem[wv];
    const int m = TOPK - rq;
    const unsigned long long pk = ((unsigned long long)pivot[wv]) << 32;
    for (int j = lane; j < e; j += 64) {
      unsigned int idx = ebuf[wv][j];
      int rank = 0;
      for (int i = 0; i < e; i++) rank += (ebuf[wv][i] < idx) ? 1 : 0;
      if (rank < rq) cand[wv][m + rank] = pk | (unsigned int)(~idx);
    }
  }

  // ---- phase 4: bitonic sort 128/row desc; low ~idx -> index-asc ties ----
  {
    const int row = tid >> 6;
    const int l = tid & 63;
    for (int k2 = 2; k2 <= TOPK; k2 <<= 1) {
      for (int j = k2 >> 1; j > 0; j >>= 1) {
        __syncthreads();
        int pos = ((l & ~(j - 1)) << 1) | (l & (j - 1));
        int ixj = pos | j;
        unsigned long long a = cand[row][pos];
        unsigned long long b = cand[row][ixj];
        bool dir = ((pos & k2) == 0);
        if ((a < b) == dir) { cand[row][pos] = b; cand[row][ixj] = a; }
      }
    }
  }
  __syncthreads();

  for (int i = tid; i < 8 * TOPK; i += 512) {
    int q = i >> 7;
    int j = i & (TOPK - 1);
    out[((size_t)h * TLEN + t0 + q) * TOPK + j] = (int)(~(unsigned int)cand[q][j]);
  }
}

extern "C" void kernel_launch(void* const* d_in, const int* in_sizes, int n_in,
                              void* d_out, int out_size, void* d_ws, size_t ws_size,
                              hipStream_t stream) {
  const float* q  = (const float*)d_in[0];
  const float* k  = (const float*)d_in[1];
  const float* Wq = (const float*)d_in[2];
  const float* Wk = (const float*)d_in[3];

  const size_t idx_elems = (size_t)NHEADS * TLEN * IDXD;   // 4M elements
  if (ws_size < 2 * idx_elems * sizeof(float)) return;     // need 32MB scratch

  float* qidx = (float*)d_ws;                  // [H][T][64] f32, 16MB
  float* kT   = (float*)d_ws + idx_elems;      // [H][64][T] f32, 16MB

  dim3 gproj(NPROJ / 64, TLEN / 64);
  proj_gemm<0><<<gproj, 256, 0, stream>>>(q, Wq, qidx);
  proj_gemm<1><<<gproj, 256, 0, stream>>>(k, Wk, kT);

  dim3 gsc(TLEN / 8, NHEADS);
  score_topk<<<gsc, 512, 0, stream>>>(qidx, kT, (int*)d_out);
}

// Round 23
// 1975.632 us; speedup vs baseline: 14.6956x; 1.6952x over previous
//
#include <hip/hip_runtime.h>
#include <stdint.h>

#define TLEN   4096
#define DMODEL 2048
#define NPROJ  1024
#define NHEADS 16
#define IDXD   64
#define TOPK   128
#define KC     512   // BLIS/AOCL zen f32 kc (verified R21: panels {512x4})

// monotonic f32 -> orderable u32 (no NaN/Inf in this data)
__device__ __forceinline__ unsigned int f32_ord(float f) {
  unsigned int u = __float_as_uint(f);
  return (u & 0x80000000u) ? ~u : (u | 0x80000000u);
}

// Tiled projection GEMM, bit-exact to verified R21 arithmetic (R22-verified):
// 4 K-panels of 512, each a zero-init sequential FMA chain, panels combined
// left-to-right with plain f32 adds.
// TRANS==0: out[h][t][d]   TRANS==1: out[h][d][t]
template<int TRANS>
__global__ __launch_bounds__(256)
void proj_gemm(const float* __restrict__ X, const float* __restrict__ W,
               float* __restrict__ out) {
  __shared__ float smem[64 * 65];
  float (*As)[64] = (float(*)[64])smem;          // [k][m]
  float (*Bs)[64] = (float(*)[64])(smem + 2048); // [k][n]
  float (*cs)[65] = (float(*)[65])smem;          // transpose staging

  const int tid = threadIdx.x;
  const int bx = blockIdx.x;   // head (64 output cols)
  const int by = blockIdx.y;   // t-tile

  const int tx = tid & 15;
  const int ty = tid >> 4;

  float acc[4][4] = {};
  float ctot[4][4];

  const int lt = tid & 7;
  const int tt = tid >> 3;
  const int bc = tid >> 4;
  const int bn = (tid & 15) * 4;

  for (int ks = 0; ks < DMODEL; ks += 32) {
    const int h2 = ks >> 7;
    const int offs = ks & 127;
    {
      const float* ap = X + ((size_t)h2 * TLEN + (size_t)by * 64) * 128 + offs + lt * 4;
      #pragma unroll
      for (int i = 0; i < 2; i++) {
        int t = tt + i * 32;
        float4 v = *(const float4*)(ap + (size_t)t * 128);
        As[lt * 4 + 0][t] = v.x;
        As[lt * 4 + 1][t] = v.y;
        As[lt * 4 + 2][t] = v.z;
        As[lt * 4 + 3][t] = v.w;
      }
    }
    {
      #pragma unroll
      for (int i = 0; i < 2; i++) {
        int c = ks + bc + i * 16;
        float4 v = *(const float4*)(W + (size_t)c * NPROJ + bx * 64 + bn);
        *(float4*)&Bs[bc + i * 16][bn] = v;
      }
    }
    __syncthreads();
    #pragma unroll
    for (int kk = 0; kk < 32; kk++) {
      float4 a = *(const float4*)&As[kk][ty * 4];
      float4 b = *(const float4*)&Bs[kk][tx * 4];
      const float av[4] = {a.x, a.y, a.z, a.w};
      const float bv[4] = {b.x, b.y, b.z, b.w};
      #pragma unroll
      for (int i = 0; i < 4; i++)
        #pragma unroll
        for (int j = 0; j < 4; j++)
          acc[i][j] = fmaf(av[i], bv[j], acc[i][j]);
    }
    __syncthreads();
    if (((ks + 32) & (KC - 1)) == 0) {           // panel boundary
      const bool first = (ks + 32 == KC);
      #pragma unroll
      for (int i = 0; i < 4; i++)
        #pragma unroll
        for (int j = 0; j < 4; j++) {
          ctot[i][j] = first ? acc[i][j] : __fadd_rn(ctot[i][j], acc[i][j]);
          acc[i][j] = 0.0f;
        }
    }
  }

  if (TRANS == 0) {
    #pragma unroll
    for (int i = 0; i < 4; i++) {
      int m = by * 64 + ty * 4 + i;
      float4 v = make_float4(ctot[i][0], ctot[i][1], ctot[i][2], ctot[i][3]);
      *(float4*)(out + ((size_t)bx * TLEN + m) * IDXD + tx * 4) = v;
    }
  } else {
    #pragma unroll
    for (int i = 0; i < 4; i++)
      #pragma unroll
      for (int j = 0; j < 4; j++)
        cs[ty * 4 + i][tx * 4 + j] = ctot[i][j];
    __syncthreads();
    const int mm = tid & 63;
    const int dg = tid >> 6;
    #pragma unroll
    for (int p = 0; p < 16; p++) {
      int d = dg + p * 4;
      out[((size_t)bx * IDXD + d) * TLEN + (size_t)by * 64 + mm] = cs[mm][d];
    }
  }
}

// Fused score + exact top-128 (R22-verified, absmax=0), with the radix
// bucket scan parallelized: wave wv owns row wv; suffix-sum via shfl_up.
__global__ __launch_bounds__(512)
void score_topk(const float* __restrict__ qidx,  // [H][T][64]
                const float* __restrict__ kT,    // [H][64][T]
                int* __restrict__ out) {         // [H][T][128]
  __shared__ float qs[8][64];
  __shared__ unsigned int hist[8][257];
  __shared__ unsigned int ebuf[8][128];
  __shared__ unsigned long long cand[8][TOPK];
  __shared__ unsigned int pivot[8];
  __shared__ int rrem[8];
  __shared__ int gcnt[8];
  __shared__ int ecnt[8];

  const int tid = threadIdx.x;
  const int lane = tid & 63;
  const int wv = tid >> 6;

  // XCD swizzle: 2 heads per XCD -> kT head slices L2-resident
  const int flat = blockIdx.y * gridDim.x + blockIdx.x;   // 0..8191
  const int nf   = (flat & 7) * 1024 + (flat >> 3);
  const int h    = nf >> 9;
  const int t0   = (nf & 511) * 8;

  if (tid < 8) { pivot[tid] = 0; rrem[tid] = TOPK; gcnt[tid] = 0; ecnt[tid] = 0; }
  for (int i = tid; i < 8 * TOPK; i += 512)
    ((unsigned long long*)cand)[i] = 0x00000000FFFFFFFFull;  // sentinel
  qs[tid >> 6][tid & 63] =
      qidx[((size_t)h * TLEN + t0 + (tid >> 6)) * IDXD + (tid & 63)];
  __syncthreads();

  // ---- phase 1: scores, strict d-ascending chain. k index = s*512 + tid ----
  float sc[8][8] = {};
  const float* kb = kT + (size_t)h * IDXD * TLEN + tid;
  for (int d = 0; d < IDXD; d++) {
    float kv[8];
    #pragma unroll
    for (int s = 0; s < 8; s++) kv[s] = kb[(size_t)d * TLEN + s * 512];
    #pragma unroll
    for (int q = 0; q < 8; q++) {
      float qv = qs[q][d];
      #pragma unroll
      for (int s = 0; s < 8; s++) sc[q][s] = fmaf(qv, kv[s], sc[q][s]);
    }
  }

  unsigned int ku[8][8];
  #pragma unroll
  for (int q = 0; q < 8; q++)
    #pragma unroll
    for (int s = 0; s < 8; s++) ku[q][s] = f32_ord(sc[q][s]);

  // ---- phase 2: 4-pass radix select, wave-parallel bucket scan ----
  for (int pass = 0; pass < 4; pass++) {
    const int shift = 24 - 8 * pass;
    const unsigned int pmask = (pass == 0) ? 0u : (0xFFFFFFFFu << (shift + 8));
    for (int i = tid; i < 8 * 257; i += 512) ((unsigned int*)hist)[i] = 0;
    __syncthreads();
    #pragma unroll
    for (int q = 0; q < 8; q++) {
      unsigned int pv = pivot[q];
      #pragma unroll
      for (int s = 0; s < 8; s++) {
        unsigned int k = ku[q][s];
        if ((k & pmask) == pv)
          atomicAdd(&hist[q][(k >> shift) & 255], 1u);
      }
    }
    __syncthreads();
    {
      // wave wv scans row wv: lane l holds buckets 255-4l..252-4l (desc order)
      const int rq = rrem[wv];
      unsigned int c0 = hist[wv][255 - 4 * lane];
      unsigned int c1 = hist[wv][254 - 4 * lane];
      unsigned int c2 = hist[wv][253 - 4 * lane];
      unsigned int c3 = hist[wv][252 - 4 * lane];
      unsigned int lsum = c0 + c1 + c2 + c3;
      unsigned int x = lsum;
      #pragma unroll
      for (int off = 1; off < 64; off <<= 1) {
        unsigned int y = __shfl_up(x, off);
        if (lane >= off) x += y;
      }
      const unsigned int excl = x - lsum;   // keys above this lane's buckets
      if ((int)excl < rq && (int)(excl + lsum) >= rq) {
        // crossing is inside this lane's 4 buckets
        unsigned int cum = excl;
        unsigned int cc[4] = {c0, c1, c2, c3};
        #pragma unroll
        for (int i = 0; i < 4; i++) {
          if ((int)(cum + cc[i]) >= rq) {
            rrem[wv] = rq - (int)cum;
            pivot[wv] |= (unsigned int)(255 - 4 * lane - i) << shift;
            break;
          }
          cum += cc[i];
        }
      }
    }
    __syncthreads();
  }

  // ---- phase 3: gather. > pivot all in; == pivot take smallest indices ----
  #pragma unroll
  for (int q = 0; q < 8; q++) {
    unsigned int pv = pivot[q];
    #pragma unroll
    for (int s = 0; s < 8; s++) {
      unsigned int k = ku[q][s];
      unsigned int idx = s * 512 + tid;
      if (k > pv) {
        int pos = atomicAdd(&gcnt[q], 1);
        if (pos < TOPK)
          cand[q][pos] = ((unsigned long long)k << 32) | (unsigned int)(~idx);
      } else if (k == pv) {
        int e = atomicAdd(&ecnt[q], 1);
        if (e < 128) ebuf[q][e] = idx;
      }
    }
  }
  __syncthreads();
  {
    int e = ecnt[wv]; if (e > 128) e = 128;
    const int rq = rrem[wv];
    const int m = TOPK - rq;
    const unsigned long long pk = ((unsigned long long)pivot[wv]) << 32;
    for (int j = lane; j < e; j += 64) {
      unsigned int idx = ebuf[wv][j];
      int rank = 0;
      for (int i = 0; i < e; i++) rank += (ebuf[wv][i] < idx) ? 1 : 0;
      if (rank < rq) cand[wv][m + rank] = pk | (unsigned int)(~idx);
    }
  }

  // ---- phase 4: bitonic sort 128/row desc; low ~idx -> index-asc ties ----
  {
    const int row = tid >> 6;
    const int l = tid & 63;
    for (int k2 = 2; k2 <= TOPK; k2 <<= 1) {
      for (int j = k2 >> 1; j > 0; j >>= 1) {
        __syncthreads();
        int pos = ((l & ~(j - 1)) << 1) | (l & (j - 1));
        int ixj = pos | j;
        unsigned long long a = cand[row][pos];
        unsigned long long b = cand[row][ixj];
        bool dir = ((pos & k2) == 0);
        if ((a < b) == dir) { cand[row][pos] = b; cand[row][ixj] = a; }
      }
    }
  }
  __syncthreads();

  for (int i = tid; i < 8 * TOPK; i += 512) {
    int q = i >> 7;
    int j = i & (TOPK - 1);
    out[((size_t)h * TLEN + t0 + q) * TOPK + j] = (int)(~(unsigned int)cand[q][j]);
  }
}

extern "C" void kernel_launch(void* const* d_in, const int* in_sizes, int n_in,
                              void* d_out, int out_size, void* d_ws, size_t ws_size,
                              hipStream_t stream) {
  const float* q  = (const float*)d_in[0];
  const float* k  = (const float*)d_in[1];
  const float* Wq = (const float*)d_in[2];
  const float* Wk = (const float*)d_in[3];

  const size_t idx_elems = (size_t)NHEADS * TLEN * IDXD;   // 4M elements
  if (ws_size < 2 * idx_elems * sizeof(float)) return;     // need 32MB scratch

  float* qidx = (float*)d_ws;                  // [H][T][64] f32, 16MB
  float* kT   = (float*)d_ws + idx_elems;      // [H][64][T] f32, 16MB

  dim3 gproj(NPROJ / 64, TLEN / 64);
  proj_gemm<0><<<gproj, 256, 0, stream>>>(q, Wq, qidx);
  proj_gemm<1><<<gproj, 256, 0, stream>>>(k, Wk, kT);

  dim3 gsc(TLEN / 8, NHEADS);
  score_topk<<<gsc, 512, 0, stream>>>(qidx, kT, (int*)d_out);
}

// Round 24
// 1935.256 us; speedup vs baseline: 15.0022x; 1.0209x over previous
//
#include <hip/hip_runtime.h>
#include <stdint.h>

#define TLEN   4096
#define DMODEL 2048
#define NPROJ  1024
#define NHEADS 16
#define IDXD   64
#define TOPK   128
#define KC     512   // BLIS/AOCL zen f32 kc (verified R21: panels {512x4})

// monotonic f32 -> orderable u32 (no NaN/Inf in this data)
__device__ __forceinline__ unsigned int f32_ord(float f) {
  unsigned int u = __float_as_uint(f);
  return (u & 0x80000000u) ? ~u : (u | 0x80000000u);
}

// Tiled projection GEMM, bit-exact to verified R21 arithmetic (R22-verified):
// 4 K-panels of 512, each a zero-init sequential FMA chain, panels combined
// left-to-right with plain f32 adds.
// TRANS==0: out[h][t][d]   TRANS==1: out[h][d][t]
template<int TRANS>
__global__ __launch_bounds__(256)
void proj_gemm(const float* __restrict__ X, const float* __restrict__ W,
               float* __restrict__ out) {
  __shared__ float smem[64 * 65];
  float (*As)[64] = (float(*)[64])smem;          // [k][m]
  float (*Bs)[64] = (float(*)[64])(smem + 2048); // [k][n]
  float (*cs)[65] = (float(*)[65])smem;          // transpose staging

  const int tid = threadIdx.x;
  const int bx = blockIdx.x;   // head (64 output cols)
  const int by = blockIdx.y;   // t-tile

  const int tx = tid & 15;
  const int ty = tid >> 4;

  float acc[4][4] = {};
  float ctot[4][4];

  const int lt = tid & 7;
  const int tt = tid >> 3;
  const int bc = tid >> 4;
  const int bn = (tid & 15) * 4;

  for (int ks = 0; ks < DMODEL; ks += 32) {
    const int h2 = ks >> 7;
    const int offs = ks & 127;
    {
      const float* ap = X + ((size_t)h2 * TLEN + (size_t)by * 64) * 128 + offs + lt * 4;
      #pragma unroll
      for (int i = 0; i < 2; i++) {
        int t = tt + i * 32;
        float4 v = *(const float4*)(ap + (size_t)t * 128);
        As[lt * 4 + 0][t] = v.x;
        As[lt * 4 + 1][t] = v.y;
        As[lt * 4 + 2][t] = v.z;
        As[lt * 4 + 3][t] = v.w;
      }
    }
    {
      #pragma unroll
      for (int i = 0; i < 2; i++) {
        int c = ks + bc + i * 16;
        float4 v = *(const float4*)(W + (size_t)c * NPROJ + bx * 64 + bn);
        *(float4*)&Bs[bc + i * 16][bn] = v;
      }
    }
    __syncthreads();
    #pragma unroll
    for (int kk = 0; kk < 32; kk++) {
      float4 a = *(const float4*)&As[kk][ty * 4];
      float4 b = *(const float4*)&Bs[kk][tx * 4];
      const float av[4] = {a.x, a.y, a.z, a.w};
      const float bv[4] = {b.x, b.y, b.z, b.w};
      #pragma unroll
      for (int i = 0; i < 4; i++)
        #pragma unroll
        for (int j = 0; j < 4; j++)
          acc[i][j] = fmaf(av[i], bv[j], acc[i][j]);
    }
    __syncthreads();
    if (((ks + 32) & (KC - 1)) == 0) {           // panel boundary
      const bool first = (ks + 32 == KC);
      #pragma unroll
      for (int i = 0; i < 4; i++)
        #pragma unroll
        for (int j = 0; j < 4; j++) {
          ctot[i][j] = first ? acc[i][j] : __fadd_rn(ctot[i][j], acc[i][j]);
          acc[i][j] = 0.0f;
        }
    }
  }

  if (TRANS == 0) {
    #pragma unroll
    for (int i = 0; i < 4; i++) {
      int m = by * 64 + ty * 4 + i;
      float4 v = make_float4(ctot[i][0], ctot[i][1], ctot[i][2], ctot[i][3]);
      *(float4*)(out + ((size_t)bx * TLEN + m) * IDXD + tx * 4) = v;
    }
  } else {
    #pragma unroll
    for (int i = 0; i < 4; i++)
      #pragma unroll
      for (int j = 0; j < 4; j++)
        cs[ty * 4 + i][tx * 4 + j] = ctot[i][j];
    __syncthreads();
    const int mm = tid & 63;
    const int dg = tid >> 6;
    #pragma unroll
    for (int p = 0; p < 16; p++) {
      int d = dg + p * 4;
      out[((size_t)bx * IDXD + d) * TLEN + (size_t)by * 64 + mm] = cs[mm][d];
    }
  }
}

// Fused score + exact top-128 (R22/R23-verified selection semantics).
// R24 change: bitonic sort moved from LDS (28 barriers, u64 bank conflicts)
// into registers via shfl_xor — wave wv sorts row wv, zero barriers.
__global__ __launch_bounds__(512)
void score_topk(const float* __restrict__ qidx,  // [H][T][64]
                const float* __restrict__ kT,    // [H][64][T]
                int* __restrict__ out) {         // [H][T][128]
  __shared__ float qs[8][64];
  __shared__ unsigned int hist[8][257];
  __shared__ unsigned int ebuf[8][128];
  __shared__ unsigned long long cand[8][TOPK];
  __shared__ unsigned int pivot[8];
  __shared__ int rrem[8];
  __shared__ int gcnt[8];
  __shared__ int ecnt[8];

  const int tid = threadIdx.x;
  const int lane = tid & 63;
  const int wv = tid >> 6;

  // XCD swizzle: 2 heads per XCD -> kT head slices L2-resident
  const int flat = blockIdx.y * gridDim.x + blockIdx.x;   // 0..8191
  const int nf   = (flat & 7) * 1024 + (flat >> 3);
  const int h    = nf >> 9;
  const int t0   = (nf & 511) * 8;

  if (tid < 8) { pivot[tid] = 0; rrem[tid] = TOPK; gcnt[tid] = 0; ecnt[tid] = 0; }
  for (int i = tid; i < 8 * TOPK; i += 512)
    ((unsigned long long*)cand)[i] = 0x00000000FFFFFFFFull;  // sentinel
  qs[tid >> 6][tid & 63] =
      qidx[((size_t)h * TLEN + t0 + (tid >> 6)) * IDXD + (tid & 63)];
  __syncthreads();

  // ---- phase 1: scores, strict d-ascending chain. k index = s*512 + tid ----
  float sc[8][8] = {};
  const float* kb = kT + (size_t)h * IDXD * TLEN + tid;
  for (int d = 0; d < IDXD; d++) {
    float kv[8];
    #pragma unroll
    for (int s = 0; s < 8; s++) kv[s] = kb[(size_t)d * TLEN + s * 512];
    #pragma unroll
    for (int q = 0; q < 8; q++) {
      float qv = qs[q][d];
      #pragma unroll
      for (int s = 0; s < 8; s++) sc[q][s] = fmaf(qv, kv[s], sc[q][s]);
    }
  }

  unsigned int ku[8][8];
  #pragma unroll
  for (int q = 0; q < 8; q++)
    #pragma unroll
    for (int s = 0; s < 8; s++) ku[q][s] = f32_ord(sc[q][s]);

  // ---- phase 2: 4-pass radix select, wave-parallel bucket scan ----
  for (int pass = 0; pass < 4; pass++) {
    const int shift = 24 - 8 * pass;
    const unsigned int pmask = (pass == 0) ? 0u : (0xFFFFFFFFu << (shift + 8));
    for (int i = tid; i < 8 * 257; i += 512) ((unsigned int*)hist)[i] = 0;
    __syncthreads();
    #pragma unroll
    for (int q = 0; q < 8; q++) {
      unsigned int pv = pivot[q];
      #pragma unroll
      for (int s = 0; s < 8; s++) {
        unsigned int k = ku[q][s];
        if ((k & pmask) == pv)
          atomicAdd(&hist[q][(k >> shift) & 255], 1u);
      }
    }
    __syncthreads();
    {
      // wave wv scans row wv: lane l holds buckets 255-4l..252-4l (desc order)
      const int rq = rrem[wv];
      unsigned int c0 = hist[wv][255 - 4 * lane];
      unsigned int c1 = hist[wv][254 - 4 * lane];
      unsigned int c2 = hist[wv][253 - 4 * lane];
      unsigned int c3 = hist[wv][252 - 4 * lane];
      unsigned int lsum = c0 + c1 + c2 + c3;
      unsigned int x = lsum;
      #pragma unroll
      for (int off = 1; off < 64; off <<= 1) {
        unsigned int y = __shfl_up(x, off);
        if (lane >= off) x += y;
      }
      const unsigned int excl = x - lsum;   // keys above this lane's buckets
      if ((int)excl < rq && (int)(excl + lsum) >= rq) {
        unsigned int cum = excl;
        unsigned int cc[4] = {c0, c1, c2, c3};
        #pragma unroll
        for (int i = 0; i < 4; i++) {
          if ((int)(cum + cc[i]) >= rq) {
            rrem[wv] = rq - (int)cum;
            pivot[wv] |= (unsigned int)(255 - 4 * lane - i) << shift;
            break;
          }
          cum += cc[i];
        }
      }
    }
    __syncthreads();
  }

  // ---- phase 3: gather. > pivot all in; == pivot take smallest indices ----
  #pragma unroll
  for (int q = 0; q < 8; q++) {
    unsigned int pv = pivot[q];
    #pragma unroll
    for (int s = 0; s < 8; s++) {
      unsigned int k = ku[q][s];
      unsigned int idx = s * 512 + tid;
      if (k > pv) {
        int pos = atomicAdd(&gcnt[q], 1);
        if (pos < TOPK)
          cand[q][pos] = ((unsigned long long)k << 32) | (unsigned int)(~idx);
      } else if (k == pv) {
        int e = atomicAdd(&ecnt[q], 1);
        if (e < 128) ebuf[q][e] = idx;
      }
    }
  }
  __syncthreads();
  {
    // wave wv owns row wv: rank equal-indices, keep rrem smallest
    int e = ecnt[wv]; if (e > 128) e = 128;
    const int rq = rrem[wv];
    const int m = TOPK - rq;
    const unsigned long long pk = ((unsigned long long)pivot[wv]) << 32;
    for (int j = lane; j < e; j += 64) {
      unsigned int idx = ebuf[wv][j];
      int rank = 0;
      for (int i = 0; i < e; i++) rank += (ebuf[wv][i] < idx) ? 1 : 0;
      if (rank < rq) cand[wv][m + rank] = pk | (unsigned int)(~idx);
    }
    // wave-local writes; wave-local reads below — no block barrier needed
  }

  // ---- phase 4: register bitonic sort, wave wv sorts row wv (desc) ----
  {
    unsigned long long x0 = cand[wv][lane];        // element index lane
    unsigned long long x1 = cand[wv][lane + 64];   // element index lane+64
    #pragma unroll
    for (int k2 = 2; k2 <= 128; k2 <<= 1) {
      #pragma unroll
      for (int j = k2 >> 1; j > 0; j >>= 1) {
        if (j == 64) {
          // in-lane pair (lane, lane+64); dir = ((lane & 128)==0) = true
          unsigned long long hi = (x0 > x1) ? x0 : x1;
          unsigned long long lo = (x0 > x1) ? x1 : x0;
          x0 = hi; x1 = lo;
        } else {
          unsigned long long y0 = __shfl_xor(x0, j);
          unsigned long long y1 = __shfl_xor(x1, j);
          const bool ilow = ((lane & j) == 0);
          const bool dir0 = ((lane & k2) == 0);         // index lane
          const bool dir1 = (((lane + 64) & k2) == 0);  // index lane+64
          x0 = (dir0 == ilow) ? (x0 > y0 ? x0 : y0) : (x0 > y0 ? y0 : x0);
          x1 = (dir1 == ilow) ? (x1 > y1 ? x1 : y1) : (x1 > y1 ? y1 : x1);
        }
      }
    }
    int* orow = out + ((size_t)h * TLEN + t0 + wv) * TOPK;
    orow[lane]      = (int)(~(unsigned int)x0);
    orow[lane + 64] = (int)(~(unsigned int)x1);
  }
}

extern "C" void kernel_launch(void* const* d_in, const int* in_sizes, int n_in,
                              void* d_out, int out_size, void* d_ws, size_t ws_size,
                              hipStream_t stream) {
  const float* q  = (const float*)d_in[0];
  const float* k  = (const float*)d_in[1];
  const float* Wq = (const float*)d_in[2];
  const float* Wk = (const float*)d_in[3];

  const size_t idx_elems = (size_t)NHEADS * TLEN * IDXD;   // 4M elements
  if (ws_size < 2 * idx_elems * sizeof(float)) return;     // need 32MB scratch

  float* qidx = (float*)d_ws;                  // [H][T][64] f32, 16MB
  float* kT   = (float*)d_ws + idx_elems;      // [H][64][T] f32, 16MB

  dim3 gproj(NPROJ / 64, TLEN / 64);
  proj_gemm<0><<<gproj, 256, 0, stream>>>(q, Wq, qidx);
  proj_gemm<1><<<gproj, 256, 0, stream>>>(k, Wk, kT);

  dim3 gsc(TLEN / 8, NHEADS);
  score_topk<<<gsc, 512, 0, stream>>>(qidx, kT, (int*)d_out);
}

// Round 25
// 1831.334 us; speedup vs baseline: 15.8536x; 1.0567x over previous
//
#include <hip/hip_runtime.h>
#include <stdint.h>

#define TLEN   4096
#define DMODEL 2048
#define NPROJ  1024
#define NHEADS 16
#define IDXD   64
#define TOPK   128
#define KC     512   // BLIS/AOCL zen f32 kc (verified R21: panels {512x4})

// monotonic f32 -> orderable u32 (no NaN/Inf in this data)
__device__ __forceinline__ unsigned int f32_ord(float f) {
  unsigned int u = __float_as_uint(f);
  return (u & 0x80000000u) ? ~u : (u | 0x80000000u);
}

// Tiled projection GEMM body, bit-exact to verified R21 arithmetic:
// 4 K-panels of 512, each a zero-init sequential FMA chain, panels combined
// left-to-right with plain f32 adds.
// TRANS==0: out[h][t][d]   TRANS==1: out[h][d][t]
template<int TRANS>
__device__ __forceinline__
void proj_body(const float* __restrict__ X, const float* __restrict__ W,
               float* __restrict__ out, float* smem) {
  float (*As)[64] = (float(*)[64])smem;          // [k][m]
  float (*Bs)[64] = (float(*)[64])(smem + 2048); // [k][n]
  float (*cs)[65] = (float(*)[65])smem;          // transpose staging

  const int tid = threadIdx.x;
  const int bx = blockIdx.x;   // head (64 output cols)
  const int by = blockIdx.y;   // t-tile

  const int tx = tid & 15;
  const int ty = tid >> 4;

  float acc[4][4] = {};
  float ctot[4][4];

  const int lt = tid & 7;
  const int tt = tid >> 3;
  const int bc = tid >> 4;
  const int bn = (tid & 15) * 4;

  for (int ks = 0; ks < DMODEL; ks += 32) {
    const int h2 = ks >> 7;
    const int offs = ks & 127;
    {
      const float* ap = X + ((size_t)h2 * TLEN + (size_t)by * 64) * 128 + offs + lt * 4;
      #pragma unroll
      for (int i = 0; i < 2; i++) {
        int t = tt + i * 32;
        float4 v = *(const float4*)(ap + (size_t)t * 128);
        As[lt * 4 + 0][t] = v.x;
        As[lt * 4 + 1][t] = v.y;
        As[lt * 4 + 2][t] = v.z;
        As[lt * 4 + 3][t] = v.w;
      }
    }
    {
      #pragma unroll
      for (int i = 0; i < 2; i++) {
        int c = ks + bc + i * 16;
        float4 v = *(const float4*)(W + (size_t)c * NPROJ + bx * 64 + bn);
        *(float4*)&Bs[bc + i * 16][bn] = v;
      }
    }
    __syncthreads();
    #pragma unroll
    for (int kk = 0; kk < 32; kk++) {
      float4 a = *(const float4*)&As[kk][ty * 4];
      float4 b = *(const float4*)&Bs[kk][tx * 4];
      const float av[4] = {a.x, a.y, a.z, a.w};
      const float bv[4] = {b.x, b.y, b.z, b.w};
      #pragma unroll
      for (int i = 0; i < 4; i++)
        #pragma unroll
        for (int j = 0; j < 4; j++)
          acc[i][j] = fmaf(av[i], bv[j], acc[i][j]);
    }
    __syncthreads();
    if (((ks + 32) & (KC - 1)) == 0) {           // panel boundary
      const bool first = (ks + 32 == KC);
      #pragma unroll
      for (int i = 0; i < 4; i++)
        #pragma unroll
        for (int j = 0; j < 4; j++) {
          ctot[i][j] = first ? acc[i][j] : __fadd_rn(ctot[i][j], acc[i][j]);
          acc[i][j] = 0.0f;
        }
    }
  }

  if (TRANS == 0) {
    #pragma unroll
    for (int i = 0; i < 4; i++) {
      int m = by * 64 + ty * 4 + i;
      float4 v = make_float4(ctot[i][0], ctot[i][1], ctot[i][2], ctot[i][3]);
      *(float4*)(out + ((size_t)bx * TLEN + m) * IDXD + tx * 4) = v;
    }
  } else {
    #pragma unroll
    for (int i = 0; i < 4; i++)
      #pragma unroll
      for (int j = 0; j < 4; j++)
        cs[ty * 4 + i][tx * 4 + j] = ctot[i][j];
    __syncthreads();
    const int mm = tid & 63;
    const int dg = tid >> 6;
    #pragma unroll
    for (int p = 0; p < 16; p++) {
      int d = dg + p * 4;
      out[((size_t)bx * IDXD + d) * TLEN + (size_t)by * 64 + mm] = cs[mm][d];
    }
  }
}

// Fused: z=0 does Q-projection (row-major), z=1 does K-projection (transposed)
__global__ __launch_bounds__(256)
void proj_both(const float* __restrict__ q, const float* __restrict__ k,
               const float* __restrict__ Wq, const float* __restrict__ Wk,
               float* __restrict__ qidx, float* __restrict__ kT) {
  __shared__ float smem[64 * 65];
  if (blockIdx.z == 0) proj_body<0>(q, Wq, qidx, smem);
  else                 proj_body<1>(k, Wk, kT, smem);
}

// Fused score + exact top-128 (R22-R24-verified selection semantics).
// R25 change: thread owns k = 8*tid .. 8*tid+7 -> two float4 loads per d
// (was 8 scalar loads, 4x the address VALU). Per-score arithmetic identical.
__global__ __launch_bounds__(512)
void score_topk(const float* __restrict__ qidx,  // [H][T][64]
                const float* __restrict__ kT,    // [H][64][T]
                int* __restrict__ out) {         // [H][T][128]
  __shared__ float qs[8][64];
  __shared__ unsigned int hist[8][257];
  __shared__ unsigned int ebuf[8][128];
  __shared__ unsigned long long cand[8][TOPK];
  __shared__ unsigned int pivot[8];
  __shared__ int rrem[8];
  __shared__ int gcnt[8];
  __shared__ int ecnt[8];

  const int tid = threadIdx.x;
  const int lane = tid & 63;
  const int wv = tid >> 6;

  // XCD swizzle: 2 heads per XCD -> kT head slices L2-resident
  const int flat = blockIdx.y * gridDim.x + blockIdx.x;   // 0..8191
  const int nf   = (flat & 7) * 1024 + (flat >> 3);
  const int h    = nf >> 9;
  const int t0   = (nf & 511) * 8;

  if (tid < 8) { pivot[tid] = 0; rrem[tid] = TOPK; gcnt[tid] = 0; ecnt[tid] = 0; }
  for (int i = tid; i < 8 * TOPK; i += 512)
    ((unsigned long long*)cand)[i] = 0x00000000FFFFFFFFull;  // sentinel
  qs[tid >> 6][tid & 63] =
      qidx[((size_t)h * TLEN + t0 + (tid >> 6)) * IDXD + (tid & 63)];
  __syncthreads();

  // ---- phase 1: scores, strict d-ascending chain. k index = 8*tid + s ----
  float sc[8][8] = {};
  const float* kb = kT + (size_t)h * IDXD * TLEN + 8 * tid;
  for (int d = 0; d < IDXD; d++) {
    const float4 va = *(const float4*)(kb + (size_t)d * TLEN);
    const float4 vb = *(const float4*)(kb + (size_t)d * TLEN + 4);
    const float kv[8] = {va.x, va.y, va.z, va.w, vb.x, vb.y, vb.z, vb.w};
    #pragma unroll
    for (int q = 0; q < 8; q++) {
      float qv = qs[q][d];
      #pragma unroll
      for (int s = 0; s < 8; s++) sc[q][s] = fmaf(qv, kv[s], sc[q][s]);
    }
  }

  unsigned int ku[8][8];
  #pragma unroll
  for (int q = 0; q < 8; q++)
    #pragma unroll
    for (int s = 0; s < 8; s++) ku[q][s] = f32_ord(sc[q][s]);

  // ---- phase 2: 4-pass radix select, wave-parallel bucket scan ----
  for (int pass = 0; pass < 4; pass++) {
    const int shift = 24 - 8 * pass;
    const unsigned int pmask = (pass == 0) ? 0u : (0xFFFFFFFFu << (shift + 8));
    for (int i = tid; i < 8 * 257; i += 512) ((unsigned int*)hist)[i] = 0;
    __syncthreads();
    #pragma unroll
    for (int q = 0; q < 8; q++) {
      unsigned int pv = pivot[q];
      #pragma unroll
      for (int s = 0; s < 8; s++) {
        unsigned int k = ku[q][s];
        if ((k & pmask) == pv)
          atomicAdd(&hist[q][(k >> shift) & 255], 1u);
      }
    }
    __syncthreads();
    {
      // wave wv scans row wv: lane l holds buckets 255-4l..252-4l (desc order)
      const int rq = rrem[wv];
      unsigned int c0 = hist[wv][255 - 4 * lane];
      unsigned int c1 = hist[wv][254 - 4 * lane];
      unsigned int c2 = hist[wv][253 - 4 * lane];
      unsigned int c3 = hist[wv][252 - 4 * lane];
      unsigned int lsum = c0 + c1 + c2 + c3;
      unsigned int x = lsum;
      #pragma unroll
      for (int off = 1; off < 64; off <<= 1) {
        unsigned int y = __shfl_up(x, off);
        if (lane >= off) x += y;
      }
      const unsigned int excl = x - lsum;   // keys above this lane's buckets
      if ((int)excl < rq && (int)(excl + lsum) >= rq) {
        unsigned int cum = excl;
        unsigned int cc[4] = {c0, c1, c2, c3};
        #pragma unroll
        for (int i = 0; i < 4; i++) {
          if ((int)(cum + cc[i]) >= rq) {
            rrem[wv] = rq - (int)cum;
            pivot[wv] |= (unsigned int)(255 - 4 * lane - i) << shift;
            break;
          }
          cum += cc[i];
        }
      }
    }
    __syncthreads();
  }

  // ---- phase 3: gather. > pivot all in; == pivot take smallest indices ----
  #pragma unroll
  for (int q = 0; q < 8; q++) {
    unsigned int pv = pivot[q];
    #pragma unroll
    for (int s = 0; s < 8; s++) {
      unsigned int k = ku[q][s];
      unsigned int idx = 8 * tid + s;
      if (k > pv) {
        int pos = atomicAdd(&gcnt[q], 1);
        if (pos < TOPK)
          cand[q][pos] = ((unsigned long long)k << 32) | (unsigned int)(~idx);
      } else if (k == pv) {
        int e = atomicAdd(&ecnt[q], 1);
        if (e < 128) ebuf[q][e] = idx;
      }
    }
  }
  __syncthreads();
  {
    // wave wv owns row wv: rank equal-indices, keep rrem smallest
    int e = ecnt[wv]; if (e > 128) e = 128;
    const int rq = rrem[wv];
    const int m = TOPK - rq;
    const unsigned long long pk = ((unsigned long long)pivot[wv]) << 32;
    for (int j = lane; j < e; j += 64) {
      unsigned int idx = ebuf[wv][j];
      int rank = 0;
      for (int i = 0; i < e; i++) rank += (ebuf[wv][i] < idx) ? 1 : 0;
      if (rank < rq) cand[wv][m + rank] = pk | (unsigned int)(~idx);
    }
    // wave-local writes; wave-local reads below — no block barrier needed
  }

  // ---- phase 4: register bitonic sort, wave wv sorts row wv (desc) ----
  {
    unsigned long long x0 = cand[wv][lane];        // element index lane
    unsigned long long x1 = cand[wv][lane + 64];   // element index lane+64
    #pragma unroll
    for (int k2 = 2; k2 <= 128; k2 <<= 1) {
      #pragma unroll
      for (int j = k2 >> 1; j > 0; j >>= 1) {
        if (j == 64) {
          unsigned long long hi = (x0 > x1) ? x0 : x1;
          unsigned long long lo = (x0 > x1) ? x1 : x0;
          x0 = hi; x1 = lo;
        } else {
          unsigned long long y0 = __shfl_xor(x0, j);
          unsigned long long y1 = __shfl_xor(x1, j);
          const bool ilow = ((lane & j) == 0);
          const bool dir0 = ((lane & k2) == 0);
          const bool dir1 = (((lane + 64) & k2) == 0);
          x0 = (dir0 == ilow) ? (x0 > y0 ? x0 : y0) : (x0 > y0 ? y0 : x0);
          x1 = (dir1 == ilow) ? (x1 > y1 ? x1 : y1) : (x1 > y1 ? y1 : x1);
        }
      }
    }
    int* orow = out + ((size_t)h * TLEN + t0 + wv) * TOPK;
    orow[lane]      = (int)(~(unsigned int)x0);
    orow[lane + 64] = (int)(~(unsigned int)x1);
  }
}

extern "C" void kernel_launch(void* const* d_in, const int* in_sizes, int n_in,
                              void* d_out, int out_size, void* d_ws, size_t ws_size,
                              hipStream_t stream) {
  const float* q  = (const float*)d_in[0];
  const float* k  = (const float*)d_in[1];
  const float* Wq = (const float*)d_in[2];
  const float* Wk = (const float*)d_in[3];

  const size_t idx_elems = (size_t)NHEADS * TLEN * IDXD;   // 4M elements
  if (ws_size < 2 * idx_elems * sizeof(float)) return;     // need 32MB scratch

  float* qidx = (float*)d_ws;                  // [H][T][64] f32, 16MB
  float* kT   = (float*)d_ws + idx_elems;      // [H][64][T] f32, 16MB

  dim3 gproj(NPROJ / 64, TLEN / 64, 2);
  proj_both<<<gproj, 256, 0, stream>>>(q, k, Wq, Wk, qidx, kT);

  dim3 gsc(TLEN / 8, NHEADS);
  score_topk<<<gsc, 512, 0, stream>>>(qidx, kT, (int*)d_out);
}